// Round 12
// baseline (186.834 us; speedup 1.0000x reference)
//
#include <hip/hip_runtime.h>

// EnhancedMoEModel: B=524288, D=32, H=64, H2=32, E=8, O=1. fp32 in/out.
// out[b] = sum_e sigmoid(relu(relu(x W1e + b1e) W2e + b2e) W3e + b3e) * probs[b,e]
//
// R20: expert-stationary waves. Evidence: 48.5us plateau at 64 waves/CU =
// LDS instruction-issue bound (120 b128/wave-iter x 12cyc); 57us at 32
// waves/CU = LDS latency on serial chains; register pipelining of LDS
// re-reads busts the 128-VGPR cap (R19: 108MB spill). Fix: each wave owns
// ONE expert; its W1/W2/W3 frags (36 VGPR) load from img ONCE and stay
// resident. Block = 8 waves = 8 experts; per iter the block does 64 rows;
// per-wave prob-weighted sigmoid partials combine via a 4KB double-buffered
// LDS buffer (1 barrier/iter, 8 iters). In-loop LDS: 6 broadcast bias
// reads/iter (was 120 b128). x read 8x redundantly but L1-resident.
//
// Fragment math (verified R8/R10 end-to-end, dtype-independent C/D layout):
// 16x16x32 MFMA with A[m=lane&15][k=8q+j], B[k=8q+j][n=lane&15],
// D[m=4q+r][n]: per-lane reg r. Hidden-unit column permutation
// hmap(mt,n)=32(mt>>1)+8(n>>2)+4(mt&1)+(n&3) makes layer-N output registers
// exactly the next layer's B-fragment. L3 A-operand = w3 replicated over
// rows -> D[m][n] = s[n] for all m (s.x valid on every lane).
//
// img layout (bytes): [0,65536) weight frags F*16 (w1: F=e*256+64mt+16q+n;
// w2: F=2048+e*256+128kb2+64mt2+16q+n); [65536,67584) b1 frags f32x4
// idx=e*16+mt*4+q; [67584,68608) b2 frags idx=e*8+mt2*4+q; [68608,69120)
// a3 frags f16x8 idx=e*4+q; [69120,69152) b3 f32[8].
//
// LDS (8KB): [0,4096) partials [2][8][64] f32 double-buffered;
//            [4096,7712) bias image copy (img bytes [65536,69152)).

typedef __attribute__((ext_vector_type(8))) _Float16 f16x8;
typedef __attribute__((ext_vector_type(2))) __fp16 h16x2;
typedef __attribute__((ext_vector_type(4))) float f32x4;
typedef union { f16x8 v; unsigned u[4]; } Fu;

__device__ __forceinline__ unsigned pkh(float lo, float hi) {
    union { h16x2 v; unsigned u; } t;
    t.v = __builtin_amdgcn_cvt_pkrtz(lo, hi);
    return t.u;
}

// packed relu on 2 x f16 (relu-after-pack == relu-before-pack for RTZ)
__device__ __forceinline__ unsigned relu2(unsigned a) {
    unsigned r;
    asm("v_pk_max_f16 %0, %1, 0" : "=v"(r) : "v"(a));
    return r;
}

__device__ __forceinline__ float sigf(float s) {
    return 1.f / (1.f + __expf(-s));
}

#define MFMA32(a, b, c) __builtin_amdgcn_mfma_f32_16x16x32_f16((a), (b), (c), 0, 0, 0)

__global__ __launch_bounds__(1024)
void build_image(const float* __restrict__ W1, const float* __restrict__ b1,
                 const float* __restrict__ W2, const float* __restrict__ b2,
                 const float* __restrict__ W3, const float* __restrict__ b3,
                 char* __restrict__ ws) {
    const int tid = threadIdx.x;
    #pragma unroll
    for (int k = 0; k < 4; ++k) {
        const int F = tid + k * 1024;
        const int e = (F >> 8) & 7, s = F & 255;
        const int qq = (s >> 4) & 3, nn = s & 15;
        const float* src;
        int stride;
        if (F < 2048) {          // W1[e][d=8qq+j][hmap(mt,nn)], j strides d
            const int mt = s >> 6;
            const int h = 32 * (mt >> 1) + 8 * (nn >> 2) + 4 * (mt & 1) + (nn & 3);
            src = W1 + (e * 32 + 8 * qq) * 64 + h;
            stride = 64;
        } else {                 // W2[e][h=32kb2+8qq+j][h2map(mt2,nn)], j strides h
            const int kb2 = (s >> 7) & 1, mt2 = (s >> 6) & 1;
            const int h2 = 8 * (nn >> 2) + 4 * mt2 + (nn & 3);
            src = W2 + (e * 64 + 32 * kb2 + 8 * qq) * 32 + h2;
            stride = 32;
        }
        union { f16x8 v; unsigned u[4]; } t;
        t.u[0] = pkh(src[0 * stride], src[1 * stride]);
        t.u[1] = pkh(src[2 * stride], src[3 * stride]);
        t.u[2] = pkh(src[4 * stride], src[5 * stride]);
        t.u[3] = pkh(src[6 * stride], src[7 * stride]);
        *(f16x8*)(ws + F * 16) = t.v;
    }
    if (tid < 128) {                       // b1 frags
        const int e = tid >> 4, mt = (tid >> 2) & 3, q = tid & 3;
        *(f32x4*)(ws + 65536 + tid * 16) =
            *(const f32x4*)(b1 + e * 64 + 32 * (mt >> 1) + 4 * (mt & 1) + 8 * q);
    } else if (tid < 192) {                // b2 frags
        const int i = tid - 128, e = i >> 3, mt2 = (i >> 2) & 1, q = i & 3;
        *(f32x4*)(ws + 67584 + i * 16) =
            *(const f32x4*)(b2 + e * 32 + 4 * mt2 + 8 * q);
    } else if (tid < 224) {                // a3 frags (pre-packed f16)
        const int i = tid - 192, e = i >> 2, q = i & 3;
        const f32x4 lo = *(const f32x4*)(W3 + e * 32 + 8 * q);
        const f32x4 hi = *(const f32x4*)(W3 + e * 32 + 8 * q + 4);
        union { f16x8 v; unsigned u[4]; } a;
        a.u[0] = pkh(lo.x, lo.y); a.u[1] = pkh(lo.z, lo.w);
        a.u[2] = pkh(hi.x, hi.y); a.u[3] = pkh(hi.z, hi.w);
        *(f16x8*)(ws + 68608 + i * 16) = a.v;
    } else if (tid < 232) {                // b3
        const int i = tid - 224;
        *(float*)(ws + 69120 + i * 4) = b3[i];
    }
}

__global__ __launch_bounds__(512, 4)
void moe_fused(const float* __restrict__ x, const float* __restrict__ probs,
               const char* __restrict__ img, float* __restrict__ out) {
    __shared__ __attribute__((aligned(16))) char lds[8192];
    const int tid = threadIdx.x;
    const int w = tid >> 6, lane = tid & 63, n = lane & 15, q = lane >> 4;
    const int e = w;                       // this wave's expert, forever

    // ---- bias image -> LDS (3616 B)
    if (tid < 226) {
        *(f32x4*)(lds + 4096 + tid * 16) = *(const f32x4*)(img + 65536 + tid * 16);
    }

    // ---- weight prologue: this expert's frags -> registers, once.
    // per-lane byte offset inside a 4-frag (1KB) tile: n*16 + q*256
    const int lo = n * 16 + q * 256;
    Fu w1r[4], w2r[2][2], a3r;
    #pragma unroll
    for (int mt = 0; mt < 4; ++mt)
        w1r[mt].v = *(const f16x8*)(img + e * 4096 + mt * 1024 + lo);
    #pragma unroll
    for (int mt2 = 0; mt2 < 2; ++mt2)
        #pragma unroll
        for (int kb2 = 0; kb2 < 2; ++kb2)
            w2r[mt2][kb2].v =
                *(const f16x8*)(img + 32768 + e * 4096 + kb2 * 2048 + mt2 * 1024 + lo);
    a3r.v = *(const f16x8*)(img + 68608 + e * 64 + q * 16);
    const float b3v = *(const float*)(img + 69120 + e * 4);

    const char* bb1 = lds + 4096 + e * 256 + q * 16;   // + mt*64
    const char* bb2 = lds + 6144 + e * 128 + q * 16;   // + mt2*64

    const int base = blockIdx.x * 512;
    __syncthreads();                       // bias copy visible

    #pragma unroll 1
    for (int it = 0; it < 8; ++it) {
        const int rb = base + it * 64;
        char* pb = lds + (it & 1) * 2048;  // partials [8][64] f32

        // x fragments for 4 row-tiles (same rows for all 8 waves; L1-hot)
        Fu xf[4];
        #pragma unroll
        for (int rt = 0; rt < 4; ++rt) {
            const float* xp = x + (size_t)(rb + rt * 16 + n) * 32 + q * 8;
            const f32x4 xa = *(const f32x4*)xp, xb = *(const f32x4*)(xp + 4);
            xf[rt].u[0] = pkh(xa.x, xa.y); xf[rt].u[1] = pkh(xa.z, xa.w);
            xf[rt].u[2] = pkh(xb.x, xb.y); xf[rt].u[3] = pkh(xb.z, xb.w);
        }
        // per-row prob for this expert
        float p[4];
        #pragma unroll
        for (int rt = 0; rt < 4; ++rt)
            p[rt] = probs[(size_t)(rb + rt * 16 + n) * 8 + e];

        // Layer 1: weights resident; bias via LDS broadcast.
        Fu P[4][2];
        #pragma unroll
        for (int mt = 0; mt < 4; ++mt) {
            const f32x4 bf = *(const f32x4*)(bb1 + mt * 64);
            f32x4 c[4];
            #pragma unroll
            for (int rt = 0; rt < 4; ++rt) c[rt] = MFMA32(w1r[mt].v, xf[rt].v, bf);
            #pragma unroll
            for (int rt = 0; rt < 4; ++rt) {
                P[rt][mt >> 1].u[(mt & 1) * 2 + 0] = relu2(pkh(c[rt].x, c[rt].y));
                P[rt][mt >> 1].u[(mt & 1) * 2 + 1] = relu2(pkh(c[rt].z, c[rt].w));
            }
        }

        // Layer 2
        Fu PC[4];
        #pragma unroll
        for (int mt2 = 0; mt2 < 2; ++mt2) {
            const f32x4 bf = *(const f32x4*)(bb2 + mt2 * 64);
            f32x4 c[4];
            #pragma unroll
            for (int rt = 0; rt < 4; ++rt) c[rt] = bf;
            #pragma unroll
            for (int kb2 = 0; kb2 < 2; ++kb2)
                #pragma unroll
                for (int rt = 0; rt < 4; ++rt)
                    c[rt] = MFMA32(w2r[mt2][kb2].v, P[rt][kb2].v, c[rt]);
            #pragma unroll
            for (int rt = 0; rt < 4; ++rt) {
                PC[rt].u[mt2 * 2 + 0] = relu2(pkh(c[rt].x, c[rt].y));
                PC[rt].u[mt2 * 2 + 1] = relu2(pkh(c[rt].z, c[rt].w));
            }
        }

        // Layer 3 + sigmoid + prob weight -> partial[e][row]
        const f32x4 cb = {b3v, b3v, b3v, b3v};
        #pragma unroll
        for (int rt = 0; rt < 4; ++rt) {
            const f32x4 s = MFMA32(a3r.v, PC[rt].v, cb);   // s.x = row n value
            const float g = sigf(s.x) * p[rt];
            if (q == 0)
                *(float*)(pb + (e * 64 + rt * 16 + n) * 4) = g;
        }

        __syncthreads();                   // partials of iter `it` complete

        // wave 0 reduces 8 partials/row and stores (coalesced 256B).
        // Safe vs next iter: others write buffer (it+1)&1; this buffer is
        // rewritten only after the *next* barrier, which wave 0 reaches
        // after finishing these reads.
        if (w == 0) {
            float s = 0.f;
            #pragma unroll
            for (int ee = 0; ee < 8; ++ee)
                s += *(const float*)(pb + (ee * 64 + lane) * 4);
            out[rb + lane] = s;
        }
    }
}

extern "C" void kernel_launch(void* const* d_in, const int* in_sizes, int n_in,
                              void* d_out, int out_size, void* d_ws, size_t ws_size,
                              hipStream_t stream) {
    const float* x     = (const float*)d_in[0];
    const float* probs = (const float*)d_in[1];
    const float* W1    = (const float*)d_in[2];
    const float* b1    = (const float*)d_in[3];
    const float* W2    = (const float*)d_in[4];
    const float* b2    = (const float*)d_in[5];
    const float* W3    = (const float*)d_in[6];
    const float* b3    = (const float*)d_in[7];

    hipLaunchKernelGGL(build_image, dim3(1), dim3(1024), 0, stream,
                       W1, b1, W2, b2, W3, b3, (char*)d_ws);
    const int nrows = in_sizes[0] / 32;          // 524288
    hipLaunchKernelGGL(moe_fused, dim3(nrows / 512), dim3(512), 0, stream,
                       x, probs, (const char*)d_ws, (float*)d_out);
}